// Round 8
// baseline (358.785 us; speedup 1.0000x reference)
//
#include <hip/hip_runtime.h>
#include <hip/hip_bf16.h>

// SelfAttention B=2,N=4096,E=512,H=8,D=64 — Round 8 (= R7 with builtin fix):
// attn: barrier-free register-only main loop. S^T=K·Q^T C-layout == A-frag of
// 16x16x16 MFMA (v_mfma_f32_16x16x16_bf16 via __builtin_amdgcn_mfma_f32_16x16x16bf16_1k),
// so P goes straight from exp2 registers into PV. K/V frags loaded directly from
// global (L2). LDS only in the one-shot epilogue reduction.
// V-transpose fused into QKV GEMM epilogue (transposed ushort4 stores).

#define ROWS 8192
#define EMB  512
#define SEQ  4096
#define HEADS 8
#define HD   64
#define QSCALE 0.18033688011112042f   // 0.125 * log2(e)

typedef __attribute__((ext_vector_type(8))) short bf16x8;
typedef __attribute__((ext_vector_type(4))) short bf16x4;
typedef __attribute__((ext_vector_type(4))) float f32x4;

#define MFMA_K16(A, B, C) __builtin_amdgcn_mfma_f32_16x16x16bf16_1k(A, B, C, 0, 0, 0)

__device__ __forceinline__ float bf16_to_f(unsigned short u) {
    union { unsigned int i; float f; } v; v.i = ((unsigned int)u) << 16; return v.f;
}
__device__ __forceinline__ unsigned short f_to_bf16(float f) {
    union { __hip_bfloat16 h; unsigned short u; } v; v.h = __float2bfloat16(f); return v.u;
}
__device__ __forceinline__ unsigned int pack_bf16_trunc(float a, float b) {
    return (__float_as_uint(a) >> 16) | (__float_as_uint(b) & 0xFFFF0000u);
}
__device__ __forceinline__ void load_lds16(const void* g, void* l) {
    __builtin_amdgcn_global_load_lds(
        (const __attribute__((address_space(1))) void*)g,
        (__attribute__((address_space(3))) void*)l, 16, 0, 0);
}

// ---- dtype detection (fp32 buffers: random halfwords -> wild exponents)
__global__ void detect_kernel(const void* x, int* flag) {
    const unsigned short* p = (const unsigned short*)x;
    int t = threadIdx.x;
    int cnt = 0;
    for (int i = 0; i < 4; ++i) {
        unsigned short u = p[t * 4 + i];
        int e = (u >> 7) & 0xFF;
        if (e >= 140) cnt++;
    }
    for (int off = 32; off > 0; off >>= 1) cnt += __shfl_down(cnt, off, 64);
    if (t == 0) *flag = (cnt > 16) ? 1 : 0;   // 1 = fp32, 0 = bf16
}

// ---- only needed when input fp32: x -> x_f (fp32 copy) + xb (bf16)
__global__ __launch_bounds__(256) void conv_x_kernel(const void* __restrict__ x,
        float* __restrict__ xf, unsigned short* __restrict__ xb, const int* __restrict__ flag) {
    if (*flag == 0) return;
    int i = (blockIdx.x * 256 + threadIdx.x) * 4;
    float4 v = *(const float4*)((const float*)x + i);
    *(float4*)(xf + i) = v;
    ushort4 u = { f_to_bf16(v.x), f_to_bf16(v.y), f_to_bf16(v.z), f_to_bf16(v.w) };
    *(ushort4*)(xb + i) = u;
}

// ---- weights [K][N] -> Wt bf16 [mat*512 + n][k]
__global__ __launch_bounds__(256) void conv_wt_kernel(
        const void* W0, const void* W1, const void* W2, const void* W3,
        unsigned short* __restrict__ Wt, const int* __restrict__ flag) {
    __shared__ float T[64][65];
    int tid = threadIdx.x;
    int kt = blockIdx.x, nt = blockIdx.y, mat = blockIdx.z;
    const void* src = (mat == 0) ? W0 : (mat == 1) ? W1 : (mat == 2) ? W2 : W3;
    int fp32 = *flag;
    for (int ii = 0; ii < 4; ++ii) {
        int idx = tid + ii * 256;
        int i = idx >> 4, j = (idx & 15) * 4;
        size_t g = (size_t)(kt * 64 + i) * 512 + nt * 64 + j;
        if (fp32) {
            float4 v = *(const float4*)((const float*)src + g);
            T[i][j] = v.x; T[i][j+1] = v.y; T[i][j+2] = v.z; T[i][j+3] = v.w;
        } else {
            ushort4 u = *(const ushort4*)((const unsigned short*)src + g);
            T[i][j] = bf16_to_f(u.x); T[i][j+1] = bf16_to_f(u.y);
            T[i][j+2] = bf16_to_f(u.z); T[i][j+3] = bf16_to_f(u.w);
        }
    }
    __syncthreads();
    for (int ii = 0; ii < 2; ++ii) {
        int idx = tid + ii * 256;
        int j = idx >> 3, ch = idx & 7;
        unsigned short pk[8];
        for (int t = 0; t < 8; ++t) pk[t] = f_to_bf16(T[ch * 8 + t][j]);
        *(bf16x8*)&Wt[(size_t)(mat * 512 + nt * 64 + j) * 512 + kt * 64 + ch * 8] = *(bf16x8*)pk;
    }
}

// ---- 6 small vectors -> bias_all fp32 [6][512]: bq,bk,bv,bo,gamma,beta
__global__ __launch_bounds__(256) void conv_small_kernel(
        const void* b0, const void* b1, const void* b2, const void* b3,
        const void* b4, const void* b5, float* __restrict__ dst, const int* __restrict__ flag) {
    int idx = blockIdx.x * 256 + threadIdx.x;
    int mat = idx >> 9, off = idx & 511;
    const void* src = (mat == 0) ? b0 : (mat == 1) ? b1 : (mat == 2) ? b2 :
                      (mat == 3) ? b3 : (mat == 4) ? b4 : b5;
    float v;
    if (*flag) v = ((const float*)src)[off];
    else       v = bf16_to_f(((const unsigned short*)src)[off]);
    dst[idx] = v;
}

// ---- MFMA GEMM: C = A * Bt^T + bias, 128x128x64 tiles. A chosen per flag.
// If VtOut != null, cols >= 1024 (V block of fused QKV) are written TRANSPOSED
// to VtOut[bh][d][seq] (bf16) instead of to C.
template <typename OutT>
__global__ __launch_bounds__(256) void gemm_mfma_kernel(
        const unsigned short* __restrict__ A_conv, const unsigned short* __restrict__ A_raw,
        const int* __restrict__ flag,
        const unsigned short* __restrict__ Bt,
        const float* __restrict__ bias, OutT* __restrict__ C, int ldc, int scale_cols,
        unsigned short* __restrict__ VtOut) {
    __shared__ unsigned short At[128 * 64];
    __shared__ unsigned short Bs[128 * 64];
    const unsigned short* A = (*flag) ? A_conv : A_raw;
    int tid = threadIdx.x;
    int wave = tid >> 6, lane = tid & 63;
    int l15 = lane & 15, quad = lane >> 4;
    int m0 = blockIdx.y * 128, n0 = blockIdx.x * 128;
    int wm = (wave & 1) * 64, wn = (wave >> 1) * 64;

    int rt = wave * 32 + (lane >> 3);
    int ch = (lane & 7) ^ ((lane >> 3) & 7);
    const unsigned short* ag = A  + (size_t)(m0 + rt) * 512 + ch * 8;
    const unsigned short* bg = Bt + (size_t)(n0 + rt) * 512 + ch * 8;

    f32x4 acc[4][4];
    for (int i = 0; i < 4; ++i) for (int j = 0; j < 4; ++j) acc[i][j] = (f32x4){0.f,0.f,0.f,0.f};

    for (int k0 = 0; k0 < 512; k0 += 64) {
        __syncthreads();
        #pragma unroll
        for (int j = 0; j < 4; ++j) {
            load_lds16(ag + (size_t)(j * 8) * 512 + k0, &At[(wave * 32 + j * 8) * 64]);
            load_lds16(bg + (size_t)(j * 8) * 512 + k0, &Bs[(wave * 32 + j * 8) * 64]);
        }
        __syncthreads();
        #pragma unroll
        for (int ks = 0; ks < 2; ++ks) {
            bf16x8 a[4], b[4];
            #pragma unroll
            for (int f = 0; f < 4; ++f) {
                int pc = ((ks * 4 + quad) ^ (l15 & 7)) * 8;
                a[f] = *(const bf16x8*)&At[(wm + f * 16 + l15) * 64 + pc];
                b[f] = *(const bf16x8*)&Bs[(wn + f * 16 + l15) * 64 + pc];
            }
            #pragma unroll
            for (int fm = 0; fm < 4; ++fm)
                #pragma unroll
                for (int fn = 0; fn < 4; ++fn)
                    acc[fm][fn] = __builtin_amdgcn_mfma_f32_16x16x32_bf16(a[fm], b[fn], acc[fm][fn], 0, 0, 0);
        }
    }
    #pragma unroll
    for (int fm = 0; fm < 4; ++fm) {
        #pragma unroll
        for (int fn = 0; fn < 4; ++fn) {
            int col = n0 + wn + fn * 16 + l15;
            float bia = bias[col];
            float sc = (col < scale_cols) ? QSCALE : 1.f;
            int rowbase = m0 + wm + fm * 16 + quad * 4;
            float v0 = (acc[fm][fn][0] + bia) * sc;
            float v1 = (acc[fm][fn][1] + bia) * sc;
            float v2 = (acc[fm][fn][2] + bia) * sc;
            float v3 = (acc[fm][fn][3] + bia) * sc;
            if (VtOut && col >= 1024) {
                // transposed V store: Vt[(b*8+h)*64 + d][n]
                int hd = col - 1024;
                int bh = (rowbase >> 12) * 8 + (hd >> 6);
                int d  = hd & 63;
                ushort4 pk = { f_to_bf16(v0), f_to_bf16(v1), f_to_bf16(v2), f_to_bf16(v3) };
                *(ushort4*)&VtOut[((size_t)(bh * 64 + d)) * SEQ + (rowbase & 4095)] = pk;
            } else {
                if constexpr (sizeof(OutT) == 2) {
                    C[(size_t)(rowbase + 0) * ldc + col] = (OutT)f_to_bf16(v0);
                    C[(size_t)(rowbase + 1) * ldc + col] = (OutT)f_to_bf16(v1);
                    C[(size_t)(rowbase + 2) * ldc + col] = (OutT)f_to_bf16(v2);
                    C[(size_t)(rowbase + 3) * ldc + col] = (OutT)f_to_bf16(v3);
                } else {
                    C[(size_t)(rowbase + 0) * ldc + col] = v0;
                    C[(size_t)(rowbase + 1) * ldc + col] = v1;
                    C[(size_t)(rowbase + 2) * ldc + col] = v2;
                    C[(size_t)(rowbase + 3) * ldc + col] = v3;
                }
            }
        }
    }
}

// ---- MFMA flash attention, register-only main loop (no LDS, no barriers).
// Block = 64 q x 4 waves; wave w owns kcols [w*32, w*32+32) of each 128-k tile.
// S^T = K·Q^T (16x16x32). Its C-layout (col=q=lane&15, row=kcol=quad*4+r) is the
// A-frag layout of 16x16x16 MFMA, so P feeds PV straight from registers.
// K/V fragments are direct global loads (L2-served, waves use disjoint kcols).
__global__ __launch_bounds__(256, 3) void attn_kernel(
        const unsigned short* __restrict__ QKV, const unsigned short* __restrict__ Vt,
        unsigned short* __restrict__ Ab) {
    __shared__ float OredBuf[4 * 32 * 68];   // epilogue only (34.8 KB)
    __shared__ float Lred[256];
    int tid = threadIdx.x;
    int w = tid >> 6, lane = tid & 63;
    int l15 = lane & 15, quad = lane >> 4;
    int qt = blockIdx.x, h = blockIdx.y, b = blockIdx.z;
    int bh = b * HEADS + h;
    size_t qrow0 = (size_t)b * SEQ + qt * 64;

    // Q fragments (B-operand of S^T): lane l15 -> q row, quad -> d chunk. Pre-scaled.
    bf16x8 aq[4][2];
    #pragma unroll
    for (int qg = 0; qg < 4; ++qg) {
        const unsigned short* qp = &QKV[(qrow0 + qg * 16 + l15) * 1536 + h * 64];
        aq[qg][0] = *(const bf16x8*)&qp[quad * 8];
        aq[qg][1] = *(const bf16x8*)&qp[32 + quad * 8];
    }
    f32x4 o[4][4];                 // [qg][db]: O[q=qg*16+quad*4+r][d=db*16+l15] partial
    #pragma unroll
    for (int qg = 0; qg < 4; ++qg)
        #pragma unroll
        for (int db = 0; db < 4; ++db) o[qg][db] = (f32x4){0.f, 0.f, 0.f, 0.f};
    float lp[4] = {0.f, 0.f, 0.f, 0.f};

    const unsigned short* kb = &QKV[((size_t)b * SEQ) * 1536 + 512 + h * 64];
    const unsigned short* vb = &Vt[((size_t)bh * 64) * SEQ];

    for (int kt = 0; kt < 32; ++kt) {
        int kc0 = kt * 128 + w * 32;           // this wave's kcol base
        // K A-fragments: lane l15 -> K row kc0+nb*16+l15, 2 x 16B per nb
        bf16x8 kn[2][2];
        #pragma unroll
        for (int nb = 0; nb < 2; ++nb) {
            const unsigned short* kr = kb + (size_t)(kc0 + nb * 16 + l15) * 1536;
            kn[nb][0] = *(const bf16x8*)&kr[quad * 8];
            kn[nb][1] = *(const bf16x8*)&kr[32 + quad * 8];
        }
        // V B-fragments (16x16x16): lane l15 -> d row, k = quad*4+j -> 8B each
        bf16x4 bv[2][4];
        #pragma unroll
        for (int nb = 0; nb < 2; ++nb)
            #pragma unroll
            for (int db = 0; db < 4; ++db)
                bv[nb][db] = *(const bf16x4*)&vb[(size_t)(db * 16 + l15) * SEQ +
                                                 kc0 + nb * 16 + quad * 4];
        #pragma unroll
        for (int nb = 0; nb < 2; ++nb) {
            #pragma unroll
            for (int qg = 0; qg < 4; ++qg) {
                f32x4 s = {0.f, 0.f, 0.f, 0.f};
                s = __builtin_amdgcn_mfma_f32_16x16x32_bf16(kn[nb][0], aq[qg][0], s, 0, 0, 0);
                s = __builtin_amdgcn_mfma_f32_16x16x32_bf16(kn[nb][1], aq[qg][1], s, 0, 0, 0);
                float p0 = __builtin_amdgcn_exp2f(s[0]);
                float p1 = __builtin_amdgcn_exp2f(s[1]);
                float p2 = __builtin_amdgcn_exp2f(s[2]);
                float p3 = __builtin_amdgcn_exp2f(s[3]);
                lp[qg] += (p0 + p1) + (p2 + p3);
                union { unsigned int u[2]; bf16x4 v; } ap;
                ap.u[0] = pack_bf16_trunc(p0, p1);
                ap.u[1] = pack_bf16_trunc(p2, p3);
                #pragma unroll
                for (int db = 0; db < 4; ++db)
                    o[qg][db] = MFMA_K16(ap.v, bv[nb][db], o[qg][db]);
            }
        }
    }

    // ---- epilogue: l over quads (shfl), O/l over waves via LDS
    #pragma unroll
    for (int qg = 0; qg < 4; ++qg) {
        float v = lp[qg];
        v += __shfl_xor(v, 16, 64);
        v += __shfl_xor(v, 32, 64);
        if (quad == 0) Lred[w * 64 + qg * 16 + l15] = v;
    }
    __syncthreads();
    float* OredW = OredBuf + w * 32 * 68;
    #pragma unroll
    for (int p = 0; p < 2; ++p) {
        #pragma unroll
        for (int qh = 0; qh < 2; ++qh) {
            int qg = p * 2 + qh;
            #pragma unroll
            for (int db = 0; db < 4; ++db)
                #pragma unroll
                for (int r = 0; r < 4; ++r)
                    OredW[(qh * 16 + quad * 4 + r) * 68 + db * 16 + l15] = o[qg][db][r];
        }
        __syncthreads();
        {
            int q_l = tid >> 3;       // 0..31
            int dg = (tid & 7) * 8;
            float acc[8] = {0.f,0.f,0.f,0.f,0.f,0.f,0.f,0.f};
            #pragma unroll
            for (int wr = 0; wr < 4; ++wr) {
                const float* src = OredBuf + wr * 32 * 68 + q_l * 68 + dg;
                float4 a = *(const float4*)&src[0];
                float4 c = *(const float4*)&src[4];
                acc[0] += a.x; acc[1] += a.y; acc[2] += a.z; acc[3] += a.w;
                acc[4] += c.x; acc[5] += c.y; acc[6] += c.z; acc[7] += c.w;
            }
            int q = p * 32 + q_l;
            float lt = Lred[q] + Lred[64 + q] + Lred[128 + q] + Lred[192 + q];
            float inv = 1.f / lt;
            unsigned short pk[8];
            #pragma unroll
            for (int i = 0; i < 8; ++i) pk[i] = f_to_bf16(acc[i] * inv);
            *(bf16x8*)&Ab[(qrow0 + q) * EMB + h * 64 + dg] = *(bf16x8*)pk;
        }
        __syncthreads();
    }
}

// ---- y = x + P; LayerNorm -> out. 4 rows per block (1 wave each).
__global__ __launch_bounds__(256) void ln_kernel(
        const float* __restrict__ xf, const unsigned short* __restrict__ xraw,
        const unsigned short* __restrict__ P,
        const float* __restrict__ gamma, const float* __restrict__ beta,
        void* __restrict__ out, const int* __restrict__ flag) {
    int row = blockIdx.x * 4 + (threadIdx.x >> 6);
    int t = threadIdx.x & 63;
    int fp32 = *flag;
    float v[8];
    float s = 0.f, ss = 0.f;
    const unsigned short* pp = &P[(size_t)row * EMB + t * 8];
    ushort4 p0 = *(const ushort4*)&pp[0];
    ushort4 p1 = *(const ushort4*)&pp[4];
    float pv[8] = { bf16_to_f(p0.x), bf16_to_f(p0.y), bf16_to_f(p0.z), bf16_to_f(p0.w),
                    bf16_to_f(p1.x), bf16_to_f(p1.y), bf16_to_f(p1.z), bf16_to_f(p1.w) };
    if (fp32) {
        const float* xp = &xf[(size_t)row * EMB + t * 8];
        for (int i = 0; i < 8; i += 4) {
            float4 x4 = *(const float4*)&xp[i];
            v[i] = x4.x + pv[i]; v[i+1] = x4.y + pv[i+1];
            v[i+2] = x4.z + pv[i+2]; v[i+3] = x4.w + pv[i+3];
        }
    } else {
        const unsigned short* xp = &xraw[(size_t)row * EMB + t * 8];
        ushort4 x0 = *(const ushort4*)&xp[0];
        ushort4 x1 = *(const ushort4*)&xp[4];
        v[0] = bf16_to_f(x0.x) + pv[0]; v[1] = bf16_to_f(x0.y) + pv[1];
        v[2] = bf16_to_f(x0.z) + pv[2]; v[3] = bf16_to_f(x0.w) + pv[3];
        v[4] = bf16_to_f(x1.x) + pv[4]; v[5] = bf16_to_f(x1.y) + pv[5];
        v[6] = bf16_to_f(x1.z) + pv[6]; v[7] = bf16_to_f(x1.w) + pv[7];
    }
    for (int i = 0; i < 8; ++i) { s += v[i]; ss += v[i] * v[i]; }
    for (int off = 32; off > 0; off >>= 1) {
        s  += __shfl_xor(s, off, 64);
        ss += __shfl_xor(ss, off, 64);
    }
    float mu = s * (1.f / 512.f);
    float var = ss * (1.f / 512.f) - mu * mu;
    float rs = rsqrtf(var + 1e-5f);
    for (int i = 0; i < 8; ++i) {
        int col = t * 8 + i;
        float y = (v[i] - mu) * rs * gamma[col] + beta[col];
        if (fp32) ((float*)out)[(size_t)row * EMB + col] = y;
        else      ((__hip_bfloat16*)out)[(size_t)row * EMB + col] = __float2bfloat16(y);
    }
}

extern "C" void kernel_launch(void* const* d_in, const int* in_sizes, int n_in,
                              void* d_out, int out_size, void* d_ws, size_t ws_size,
                              hipStream_t stream) {
    char* ws = (char*)d_ws;
    int* flag = (int*)ws;
    char* p = ws + 256;
    float* x_f  = (float*)p;           p += (size_t)ROWS * EMB * 4;          // 16MB
    float* bias_all = (float*)p;       p += 6 * 512 * 4;
    unsigned short* Wt   = (unsigned short*)p; p += (size_t)2048 * 512 * 2;  // 2MB
    unsigned short* QKVb = (unsigned short*)p; p += (size_t)ROWS * 1536 * 2; // 24MB
    unsigned short* Vt   = (unsigned short*)p; p += (size_t)16 * HD * SEQ * 2; // 8MB
    // shared region: xb (conv_x -> QKV gemm) then Ab (attn -> O-proj)
    unsigned short* xb = (unsigned short*)p;
    unsigned short* Ab = (unsigned short*)p;   p += (size_t)ROWS * EMB * 2;  // 8MB
    unsigned short* Pb = (unsigned short*)p;   p += (size_t)ROWS * EMB * 2;  // 8MB

    detect_kernel<<<1, 64, 0, stream>>>(d_in[0], flag);

    conv_x_kernel<<<ROWS * EMB / 1024, 256, 0, stream>>>(d_in[0], x_f, xb, flag);
    conv_wt_kernel<<<dim3(8, 8, 4), 256, 0, stream>>>(d_in[1], d_in[3], d_in[5], d_in[7], Wt, flag);
    conv_small_kernel<<<12, 256, 0, stream>>>(d_in[2], d_in[4], d_in[6], d_in[8], d_in[9], d_in[10],
                                              bias_all, flag);

    // fused QKV: N=1536; Q cols pre-scaled by QSCALE; V cols written transposed to Vt
    gemm_mfma_kernel<unsigned short><<<dim3(12, 64), 256, 0, stream>>>(
        xb, (const unsigned short*)d_in[0], flag, Wt, bias_all, QKVb, 1536, 512, Vt);

    attn_kernel<<<dim3(SEQ / 64, HEADS, 2), 256, 0, stream>>>(QKVb, Vt, Ab);

    // O-proj -> bf16
    gemm_mfma_kernel<unsigned short><<<dim3(4, 64), 256, 0, stream>>>(
        Ab, Ab, flag, Wt + (size_t)1536 * 512, bias_all + 1536, Pb, 512, 0,
        (unsigned short*)nullptr);

    ln_kernel<<<ROWS / 4, 256, 0, stream>>>(x_f, (const unsigned short*)d_in[0], Pb,
                                            bias_all + 4 * 512, bias_all + 5 * 512, d_out, flag);
}

// Round 9
// 262.808 us; speedup vs baseline: 1.3652x; 1.3652x over previous
//
#include <hip/hip_runtime.h>
#include <hip/hip_bf16.h>

// SelfAttention B=2,N=4096,E=512,H=8,D=64 — Round 9:
// attn = R4 body (best measured: 119us) + split-K=2 for 3 blocks/CU occupancy:
//   grid 1024 (1-D, XCD-swizzled: xcd=lin&7 -> 4 (b,h,s)-groups per XCD, K/V fits 4MB L2),
//   KT=128 LDS staging unchanged, fp32 row-contiguous partial stores + merge kernel.
// V-transpose stays fused in QKV GEMM epilogue (validated R8).

#define ROWS 8192
#define EMB  512
#define SEQ  4096
#define HEADS 8
#define HD   64
#define SPLIT 2
#define QSCALE 0.18033688011112042f   // 0.125 * log2(e)

typedef __attribute__((ext_vector_type(8))) short bf16x8;
typedef __attribute__((ext_vector_type(4))) float f32x4;

__device__ __forceinline__ float bf16_to_f(unsigned short u) {
    union { unsigned int i; float f; } v; v.i = ((unsigned int)u) << 16; return v.f;
}
__device__ __forceinline__ unsigned short f_to_bf16(float f) {
    union { __hip_bfloat16 h; unsigned short u; } v; v.h = __float2bfloat16(f); return v.u;
}
__device__ __forceinline__ unsigned short f_to_bf16_trunc(float f) {
    return (unsigned short)(__float_as_uint(f) >> 16);
}
__device__ __forceinline__ void load_lds16(const void* g, void* l) {
    __builtin_amdgcn_global_load_lds(
        (const __attribute__((address_space(1))) void*)g,
        (__attribute__((address_space(3))) void*)l, 16, 0, 0);
}

// ---- dtype detection (fp32 buffers: random halfwords -> wild exponents)
__global__ void detect_kernel(const void* x, int* flag) {
    const unsigned short* p = (const unsigned short*)x;
    int t = threadIdx.x;
    int cnt = 0;
    for (int i = 0; i < 4; ++i) {
        unsigned short u = p[t * 4 + i];
        int e = (u >> 7) & 0xFF;
        if (e >= 140) cnt++;
    }
    for (int off = 32; off > 0; off >>= 1) cnt += __shfl_down(cnt, off, 64);
    if (t == 0) *flag = (cnt > 16) ? 1 : 0;   // 1 = fp32, 0 = bf16
}

// ---- only needed when input fp32: x -> x_f (fp32 copy) + xb (bf16)
__global__ __launch_bounds__(256) void conv_x_kernel(const void* __restrict__ x,
        float* __restrict__ xf, unsigned short* __restrict__ xb, const int* __restrict__ flag) {
    if (*flag == 0) return;
    int i = (blockIdx.x * 256 + threadIdx.x) * 4;
    float4 v = *(const float4*)((const float*)x + i);
    *(float4*)(xf + i) = v;
    ushort4 u = { f_to_bf16(v.x), f_to_bf16(v.y), f_to_bf16(v.z), f_to_bf16(v.w) };
    *(ushort4*)(xb + i) = u;
}

// ---- weights [K][N] -> Wt bf16 [mat*512 + n][k]
__global__ __launch_bounds__(256) void conv_wt_kernel(
        const void* W0, const void* W1, const void* W2, const void* W3,
        unsigned short* __restrict__ Wt, const int* __restrict__ flag) {
    __shared__ float T[64][65];
    int tid = threadIdx.x;
    int kt = blockIdx.x, nt = blockIdx.y, mat = blockIdx.z;
    const void* src = (mat == 0) ? W0 : (mat == 1) ? W1 : (mat == 2) ? W2 : W3;
    int fp32 = *flag;
    for (int ii = 0; ii < 4; ++ii) {
        int idx = tid + ii * 256;
        int i = idx >> 4, j = (idx & 15) * 4;
        size_t g = (size_t)(kt * 64 + i) * 512 + nt * 64 + j;
        if (fp32) {
            float4 v = *(const float4*)((const float*)src + g);
            T[i][j] = v.x; T[i][j+1] = v.y; T[i][j+2] = v.z; T[i][j+3] = v.w;
        } else {
            ushort4 u = *(const ushort4*)((const unsigned short*)src + g);
            T[i][j] = bf16_to_f(u.x); T[i][j+1] = bf16_to_f(u.y);
            T[i][j+2] = bf16_to_f(u.z); T[i][j+3] = bf16_to_f(u.w);
        }
    }
    __syncthreads();
    for (int ii = 0; ii < 2; ++ii) {
        int idx = tid + ii * 256;
        int j = idx >> 3, ch = idx & 7;
        unsigned short pk[8];
        for (int t = 0; t < 8; ++t) pk[t] = f_to_bf16(T[ch * 8 + t][j]);
        *(bf16x8*)&Wt[(size_t)(mat * 512 + nt * 64 + j) * 512 + kt * 64 + ch * 8] = *(bf16x8*)pk;
    }
}

// ---- 6 small vectors -> bias_all fp32 [6][512]: bq,bk,bv,bo,gamma,beta
__global__ __launch_bounds__(256) void conv_small_kernel(
        const void* b0, const void* b1, const void* b2, const void* b3,
        const void* b4, const void* b5, float* __restrict__ dst, const int* __restrict__ flag) {
    int idx = blockIdx.x * 256 + threadIdx.x;
    int mat = idx >> 9, off = idx & 511;
    const void* src = (mat == 0) ? b0 : (mat == 1) ? b1 : (mat == 2) ? b2 :
                      (mat == 3) ? b3 : (mat == 4) ? b4 : b5;
    float v;
    if (*flag) v = ((const float*)src)[off];
    else       v = bf16_to_f(((const unsigned short*)src)[off]);
    dst[idx] = v;
}

// ---- MFMA GEMM: C = A * Bt^T + bias, 128x128x64 tiles. A chosen per flag.
// If VtOut != null, cols >= 1024 (V block of fused QKV) are written TRANSPOSED
// to VtOut[bh][d][seq] (bf16) instead of to C.
template <typename OutT>
__global__ __launch_bounds__(256) void gemm_mfma_kernel(
        const unsigned short* __restrict__ A_conv, const unsigned short* __restrict__ A_raw,
        const int* __restrict__ flag,
        const unsigned short* __restrict__ Bt,
        const float* __restrict__ bias, OutT* __restrict__ C, int ldc, int scale_cols,
        unsigned short* __restrict__ VtOut) {
    __shared__ unsigned short At[128 * 64];
    __shared__ unsigned short Bs[128 * 64];
    const unsigned short* A = (*flag) ? A_conv : A_raw;
    int tid = threadIdx.x;
    int wave = tid >> 6, lane = tid & 63;
    int l15 = lane & 15, quad = lane >> 4;
    int m0 = blockIdx.y * 128, n0 = blockIdx.x * 128;
    int wm = (wave & 1) * 64, wn = (wave >> 1) * 64;

    int rt = wave * 32 + (lane >> 3);
    int ch = (lane & 7) ^ ((lane >> 3) & 7);
    const unsigned short* ag = A  + (size_t)(m0 + rt) * 512 + ch * 8;
    const unsigned short* bg = Bt + (size_t)(n0 + rt) * 512 + ch * 8;

    f32x4 acc[4][4];
    for (int i = 0; i < 4; ++i) for (int j = 0; j < 4; ++j) acc[i][j] = (f32x4){0.f,0.f,0.f,0.f};

    for (int k0 = 0; k0 < 512; k0 += 64) {
        __syncthreads();
        #pragma unroll
        for (int j = 0; j < 4; ++j) {
            load_lds16(ag + (size_t)(j * 8) * 512 + k0, &At[(wave * 32 + j * 8) * 64]);
            load_lds16(bg + (size_t)(j * 8) * 512 + k0, &Bs[(wave * 32 + j * 8) * 64]);
        }
        __syncthreads();
        #pragma unroll
        for (int ks = 0; ks < 2; ++ks) {
            bf16x8 a[4], b[4];
            #pragma unroll
            for (int f = 0; f < 4; ++f) {
                int pc = ((ks * 4 + quad) ^ (l15 & 7)) * 8;
                a[f] = *(const bf16x8*)&At[(wm + f * 16 + l15) * 64 + pc];
                b[f] = *(const bf16x8*)&Bs[(wn + f * 16 + l15) * 64 + pc];
            }
            #pragma unroll
            for (int fm = 0; fm < 4; ++fm)
                #pragma unroll
                for (int fn = 0; fn < 4; ++fn)
                    acc[fm][fn] = __builtin_amdgcn_mfma_f32_16x16x32_bf16(a[fm], b[fn], acc[fm][fn], 0, 0, 0);
        }
    }
    #pragma unroll
    for (int fm = 0; fm < 4; ++fm) {
        #pragma unroll
        for (int fn = 0; fn < 4; ++fn) {
            int col = n0 + wn + fn * 16 + l15;
            float bia = bias[col];
            float sc = (col < scale_cols) ? QSCALE : 1.f;
            int rowbase = m0 + wm + fm * 16 + quad * 4;
            float v0 = (acc[fm][fn][0] + bia) * sc;
            float v1 = (acc[fm][fn][1] + bia) * sc;
            float v2 = (acc[fm][fn][2] + bia) * sc;
            float v3 = (acc[fm][fn][3] + bia) * sc;
            if (VtOut && col >= 1024) {
                // transposed V store: Vt[(b*8+h)*64 + d][n]
                int hd = col - 1024;
                int bh = (rowbase >> 12) * 8 + (hd >> 6);
                int d  = hd & 63;
                ushort4 pk = { f_to_bf16(v0), f_to_bf16(v1), f_to_bf16(v2), f_to_bf16(v3) };
                *(ushort4*)&VtOut[((size_t)(bh * 64 + d)) * SEQ + (rowbase & 4095)] = pk;
            } else {
                if constexpr (sizeof(OutT) == 2) {
                    C[(size_t)(rowbase + 0) * ldc + col] = (OutT)f_to_bf16(v0);
                    C[(size_t)(rowbase + 1) * ldc + col] = (OutT)f_to_bf16(v1);
                    C[(size_t)(rowbase + 2) * ldc + col] = (OutT)f_to_bf16(v2);
                    C[(size_t)(rowbase + 3) * ldc + col] = (OutT)f_to_bf16(v3);
                } else {
                    C[(size_t)(rowbase + 0) * ldc + col] = v0;
                    C[(size_t)(rowbase + 1) * ldc + col] = v1;
                    C[(size_t)(rowbase + 2) * ldc + col] = v2;
                    C[(size_t)(rowbase + 3) * ldc + col] = v3;
                }
            }
        }
    }
}

// ---- MFMA flash attention (R4 body) + split-K=2. 1-D grid 1024, XCD-swizzled:
// xcd = lin&7, slot = lin>>3; grp = xcd + 8*(slot>>5) in 0..31 -> (h, b, s);
// qt = slot&31. Each XCD sees 4 (b,h,s) groups -> K/V working set ~4MB = its L2.
// Block = 4 waves x 32 q-rows (128 q), KT=128; fp32 partial O + l stores.
__global__ __launch_bounds__(256, 3) void attn_kernel(
        const unsigned short* __restrict__ QKV, const unsigned short* __restrict__ Vt,
        float* __restrict__ Opart, float* __restrict__ Lpart) {
    __shared__ unsigned short Ks[128 * 64];      // [krow][d] xor-swizzled chunks
    __shared__ unsigned short Vs[64 * 128];      // [d][krow] xor-swizzled chunks
    __shared__ unsigned short Ps[4][32][40];     // per-wave P [q][kcol 0..31]
    int tid = threadIdx.x;
    int wave = tid >> 6, lane = tid & 63;
    int l15 = lane & 15, quad = lane >> 4;
    int lin = blockIdx.x;
    int xcd = lin & 7, slot = lin >> 3;
    int grp = xcd + 8 * (slot >> 5);             // 0..31
    int qt = slot & 31;
    int h = grp & 7, b = (grp >> 3) & 1, s = grp >> 4;
    int bh = b * HEADS + h;
    int k0base = s * (SEQ / SPLIT);              // 0 or 2048
    int key = l15 & 7;
    size_t qrow0 = (size_t)b * SEQ + qt * 128 + wave * 32;

    bf16x8 aq[2][2];
    #pragma unroll
    for (int t = 0; t < 2; ++t) {
        const unsigned short* qp = &QKV[(qrow0 + t * 16 + l15) * 1536 + h * 64];
        aq[t][0] = *(const bf16x8*)&qp[quad * 8];
        aq[t][1] = *(const bf16x8*)&qp[32 + quad * 8];
    }

    f32x4 o[2][4];
    #pragma unroll
    for (int t = 0; t < 2; ++t)
        #pragma unroll
        for (int db = 0; db < 4; ++db) o[t][db] = (f32x4){0.f,0.f,0.f,0.f};
    float lp[2][4] = {{0.f,0.f,0.f,0.f},{0.f,0.f,0.f,0.f}};

    int krt = wave * 32 + (lane >> 3);
    int kch = (lane & 7) ^ ((lane >> 3) & 7);
    const unsigned short* kg = &QKV[((size_t)b * SEQ + k0base + krt) * 1536 + 512 + h * 64 + kch * 8];

    for (int kt = 0; kt < SEQ / SPLIT / 128; ++kt) {
        __syncthreads();
        #pragma unroll
        for (int j = 0; j < 4; ++j) {
            load_lds16(kg + (size_t)(kt * 128 + j * 8) * 1536, &Ks[(wave * 32 + j * 8) * 64]);
            int d = wave * 16 + j * 4 + (lane >> 4);
            int vch = (lane & 15) ^ (d & 7);
            load_lds16(&Vt[((size_t)bh * 64 + d) * SEQ + k0base + kt * 128 + vch * 8],
                       &Vs[(wave * 16 + j * 4) * 128]);
        }
        __syncthreads();

        #pragma unroll
        for (int ks = 0; ks < 4; ++ks) {
            // S = Qs K^T for kcols ks*32..ks*32+31 ; exp2 fused, P -> LDS (truncated bf16)
            #pragma unroll
            for (int nn = 0; nn < 2; ++nn) {
                int nb = ks * 2 + nn;
                int row = (nb * 16 + l15) * 64;
                bf16x8 bk0 = *(const bf16x8*)&Ks[row + ((0 + quad) ^ key) * 8];
                bf16x8 bk1 = *(const bf16x8*)&Ks[row + ((4 + quad) ^ key) * 8];
                #pragma unroll
                for (int t = 0; t < 2; ++t) {
                    f32x4 z = {0.f, 0.f, 0.f, 0.f};
                    z = __builtin_amdgcn_mfma_f32_16x16x32_bf16(aq[t][0], bk0, z, 0, 0, 0);
                    z = __builtin_amdgcn_mfma_f32_16x16x32_bf16(aq[t][1], bk1, z, 0, 0, 0);
                    #pragma unroll
                    for (int r = 0; r < 4; ++r) {
                        float p = __builtin_amdgcn_exp2f(z[r]);
                        lp[t][r] += p;
                        Ps[wave][t * 16 + quad * 4 + r][nn * 16 + l15] = f_to_bf16_trunc(p);
                    }
                }
            }
            asm volatile("s_waitcnt lgkmcnt(0)" ::: "memory");
            bf16x8 ap0 = *(const bf16x8*)&Ps[wave][l15][quad * 8];
            bf16x8 ap1 = *(const bf16x8*)&Ps[wave][16 + l15][quad * 8];
            #pragma unroll
            for (int db = 0; db < 4; ++db) {
                bf16x8 bv = *(const bf16x8*)&Vs[(db * 16 + l15) * 128 + ((ks * 4 + quad) ^ key) * 8];
                o[0][db] = __builtin_amdgcn_mfma_f32_16x16x32_bf16(ap0, bv, o[0][db], 0, 0, 0);
                o[1][db] = __builtin_amdgcn_mfma_f32_16x16x32_bf16(ap1, bv, o[1][db], 0, 0, 0);
            }
        }
    }
    #pragma unroll
    for (int t = 0; t < 2; ++t)
        #pragma unroll
        for (int r = 0; r < 4; ++r) {
            float sum = lp[t][r];
            #pragma unroll
            for (int off = 1; off < 16; off <<= 1) sum += __shfl_xor(sum, off, 64);
            size_t row = qrow0 + t * 16 + quad * 4 + r;
            if (l15 == 0) Lpart[((size_t)s * ROWS + row) * 8 + h] = sum;
            #pragma unroll
            for (int db = 0; db < 4; ++db)
                Opart[((size_t)s * ROWS + row) * EMB + h * 64 + db * 16 + l15] = o[t][db][r];
        }
}

// ---- merge split-K partials: Ab = (sum_s O_s) / (sum_s l_s), bf16
__global__ __launch_bounds__(256) void merge_kernel(
        const float* __restrict__ Opart, const float* __restrict__ Lpart,
        unsigned short* __restrict__ Ab) {
    int idx4 = (blockIdx.x * 256 + threadIdx.x) * 4;
    int row = idx4 >> 9;
    int h = (idx4 & 511) >> 6;
    float l = 0.f;
    float acc[4] = {0.f, 0.f, 0.f, 0.f};
    #pragma unroll
    for (int s = 0; s < SPLIT; ++s) {
        l += Lpart[((size_t)s * ROWS + row) * 8 + h];
        float4 u = *(const float4*)&Opart[(size_t)s * ROWS * EMB + idx4];
        acc[0] += u.x; acc[1] += u.y; acc[2] += u.z; acc[3] += u.w;
    }
    float inv = 1.f / l;
    ushort4 out = { f_to_bf16(acc[0] * inv), f_to_bf16(acc[1] * inv),
                    f_to_bf16(acc[2] * inv), f_to_bf16(acc[3] * inv) };
    *(ushort4*)&Ab[idx4] = out;
}

// ---- y = x + P; LayerNorm -> out. 4 rows per block (1 wave each).
__global__ __launch_bounds__(256) void ln_kernel(
        const float* __restrict__ xf, const unsigned short* __restrict__ xraw,
        const unsigned short* __restrict__ P,
        const float* __restrict__ gamma, const float* __restrict__ beta,
        void* __restrict__ out, const int* __restrict__ flag) {
    int row = blockIdx.x * 4 + (threadIdx.x >> 6);
    int t = threadIdx.x & 63;
    int fp32 = *flag;
    float v[8];
    float s = 0.f, ss = 0.f;
    const unsigned short* pp = &P[(size_t)row * EMB + t * 8];
    ushort4 p0 = *(const ushort4*)&pp[0];
    ushort4 p1 = *(const ushort4*)&pp[4];
    float pv[8] = { bf16_to_f(p0.x), bf16_to_f(p0.y), bf16_to_f(p0.z), bf16_to_f(p0.w),
                    bf16_to_f(p1.x), bf16_to_f(p1.y), bf16_to_f(p1.z), bf16_to_f(p1.w) };
    if (fp32) {
        const float* xp = &xf[(size_t)row * EMB + t * 8];
        for (int i = 0; i < 8; i += 4) {
            float4 x4 = *(const float4*)&xp[i];
            v[i] = x4.x + pv[i]; v[i+1] = x4.y + pv[i+1];
            v[i+2] = x4.z + pv[i+2]; v[i+3] = x4.w + pv[i+3];
        }
    } else {
        const unsigned short* xp = &xraw[(size_t)row * EMB + t * 8];
        ushort4 x0 = *(const ushort4*)&xp[0];
        ushort4 x1 = *(const ushort4*)&xp[4];
        v[0] = bf16_to_f(x0.x) + pv[0]; v[1] = bf16_to_f(x0.y) + pv[1];
        v[2] = bf16_to_f(x0.z) + pv[2]; v[3] = bf16_to_f(x0.w) + pv[3];
        v[4] = bf16_to_f(x1.x) + pv[4]; v[5] = bf16_to_f(x1.y) + pv[5];
        v[6] = bf16_to_f(x1.z) + pv[6]; v[7] = bf16_to_f(x1.w) + pv[7];
    }
    for (int i = 0; i < 8; ++i) { s += v[i]; ss += v[i] * v[i]; }
    for (int off = 32; off > 0; off >>= 1) {
        s  += __shfl_xor(s, off, 64);
        ss += __shfl_xor(ss, off, 64);
    }
    float mu = s * (1.f / 512.f);
    float var = ss * (1.f / 512.f) - mu * mu;
    float rs = rsqrtf(var + 1e-5f);
    for (int i = 0; i < 8; ++i) {
        int col = t * 8 + i;
        float y = (v[i] - mu) * rs * gamma[col] + beta[col];
        if (fp32) ((float*)out)[(size_t)row * EMB + col] = y;
        else      ((__hip_bfloat16*)out)[(size_t)row * EMB + col] = __float2bfloat16(y);
    }
}

extern "C" void kernel_launch(void* const* d_in, const int* in_sizes, int n_in,
                              void* d_out, int out_size, void* d_ws, size_t ws_size,
                              hipStream_t stream) {
    char* ws = (char*)d_ws;
    int* flag = (int*)ws;
    char* p = ws + 256;
    float* x_f  = (float*)p;           p += (size_t)ROWS * EMB * 4;          // 16MB
    float* bias_all = (float*)p;       p += 6 * 512 * 4;
    unsigned short* Wt   = (unsigned short*)p; p += (size_t)2048 * 512 * 2;  // 2MB
    unsigned short* QKVb = (unsigned short*)p; p += (size_t)ROWS * 1536 * 2; // 24MB
    unsigned short* Vt   = (unsigned short*)p; p += (size_t)16 * HD * SEQ * 2; // 8MB
    // shared region A: xb (conv_x -> QKV gemm) then Ab (merge -> O-proj)
    unsigned short* xb = (unsigned short*)p;
    unsigned short* Ab = (unsigned short*)p;   p += (size_t)ROWS * EMB * 2;  // 8MB
    // shared region B: Opart fp32 (attn -> merge) then Pb (O-proj -> ln)
    float* Opart = (float*)p;
    unsigned short* Pb = (unsigned short*)p;   p += (size_t)SPLIT * ROWS * EMB * 4; // 32MB
    float* Lpart = (float*)p;          p += (size_t)SPLIT * ROWS * 8 * 4;    // 0.5MB

    detect_kernel<<<1, 64, 0, stream>>>(d_in[0], flag);

    conv_x_kernel<<<ROWS * EMB / 1024, 256, 0, stream>>>(d_in[0], x_f, xb, flag);
    conv_wt_kernel<<<dim3(8, 8, 4), 256, 0, stream>>>(d_in[1], d_in[3], d_in[5], d_in[7], Wt, flag);
    conv_small_kernel<<<12, 256, 0, stream>>>(d_in[2], d_in[4], d_in[6], d_in[8], d_in[9], d_in[10],
                                              bias_all, flag);

    // fused QKV: N=1536; Q cols pre-scaled by QSCALE; V cols written transposed to Vt
    gemm_mfma_kernel<unsigned short><<<dim3(12, 64), 256, 0, stream>>>(
        xb, (const unsigned short*)d_in[0], flag, Wt, bias_all, QKVb, 1536, 512, Vt);

    attn_kernel<<<dim3(32 * HEADS * 2 * SPLIT), 256, 0, stream>>>(QKVb, Vt, Opart, Lpart);

    merge_kernel<<<ROWS * EMB / 1024, 256, 0, stream>>>(Opart, Lpart, Ab);

    // O-proj -> bf16
    gemm_mfma_kernel<unsigned short><<<dim3(4, 64), 256, 0, stream>>>(
        Ab, Ab, flag, Wt + (size_t)1536 * 512, bias_all + 1536, Pb, 512, 0,
        (unsigned short*)nullptr);

    ln_kernel<<<ROWS / 4, 256, 0, stream>>>(x_f, (const unsigned short*)d_in[0], Pb,
                                            bias_all + 4 * 512, bias_all + 5 * 512, d_out, flag);
}

// Round 10
// 255.426 us; speedup vs baseline: 1.4047x; 1.0289x over previous
//
#include <hip/hip_runtime.h>
#include <hip/hip_bf16.h>

// SelfAttention B=2,N=4096,E=512,H=8,D=64 — Round 10:
// attn: R4 LDS staging + R8 register-P (S^T=K·Q^T -> exp2 -> K16 PV direct from regs),
// 2q x 2k wave split (wave = 32q x 64kcols), split-K=2 + XCD swizzle (R9-validated).
// LDS/iter: 8 b128 (K frags) + 16 b64 (V frags) — no Ps round trip (R9 was LDS-pipe-bound).

#define ROWS 8192
#define EMB  512
#define SEQ  4096
#define HEADS 8
#define HD   64
#define SPLIT 2
#define QSCALE 0.18033688011112042f   // 0.125 * log2(e)

typedef __attribute__((ext_vector_type(8))) short bf16x8;
typedef __attribute__((ext_vector_type(4))) short bf16x4;
typedef __attribute__((ext_vector_type(4))) float f32x4;

#define MFMA_K16(A, B, C) __builtin_amdgcn_mfma_f32_16x16x16bf16_1k(A, B, C, 0, 0, 0)

__device__ __forceinline__ float bf16_to_f(unsigned short u) {
    union { unsigned int i; float f; } v; v.i = ((unsigned int)u) << 16; return v.f;
}
__device__ __forceinline__ unsigned short f_to_bf16(float f) {
    union { __hip_bfloat16 h; unsigned short u; } v; v.h = __float2bfloat16(f); return v.u;
}
__device__ __forceinline__ unsigned int pack_bf16_trunc(float a, float b) {
    return (__float_as_uint(a) >> 16) | (__float_as_uint(b) & 0xFFFF0000u);
}
__device__ __forceinline__ void load_lds16(const void* g, void* l) {
    __builtin_amdgcn_global_load_lds(
        (const __attribute__((address_space(1))) void*)g,
        (__attribute__((address_space(3))) void*)l, 16, 0, 0);
}

// ---- dtype detection (fp32 buffers: random halfwords -> wild exponents)
__global__ void detect_kernel(const void* x, int* flag) {
    const unsigned short* p = (const unsigned short*)x;
    int t = threadIdx.x;
    int cnt = 0;
    for (int i = 0; i < 4; ++i) {
        unsigned short u = p[t * 4 + i];
        int e = (u >> 7) & 0xFF;
        if (e >= 140) cnt++;
    }
    for (int off = 32; off > 0; off >>= 1) cnt += __shfl_down(cnt, off, 64);
    if (t == 0) *flag = (cnt > 16) ? 1 : 0;   // 1 = fp32, 0 = bf16
}

// ---- only needed when input fp32: x -> x_f (fp32 copy) + xb (bf16)
__global__ __launch_bounds__(256) void conv_x_kernel(const void* __restrict__ x,
        float* __restrict__ xf, unsigned short* __restrict__ xb, const int* __restrict__ flag) {
    if (*flag == 0) return;
    int i = (blockIdx.x * 256 + threadIdx.x) * 4;
    float4 v = *(const float4*)((const float*)x + i);
    *(float4*)(xf + i) = v;
    ushort4 u = { f_to_bf16(v.x), f_to_bf16(v.y), f_to_bf16(v.z), f_to_bf16(v.w) };
    *(ushort4*)(xb + i) = u;
}

// ---- weights [K][N] -> Wt bf16 [mat*512 + n][k]
__global__ __launch_bounds__(256) void conv_wt_kernel(
        const void* W0, const void* W1, const void* W2, const void* W3,
        unsigned short* __restrict__ Wt, const int* __restrict__ flag) {
    __shared__ float T[64][65];
    int tid = threadIdx.x;
    int kt = blockIdx.x, nt = blockIdx.y, mat = blockIdx.z;
    const void* src = (mat == 0) ? W0 : (mat == 1) ? W1 : (mat == 2) ? W2 : W3;
    int fp32 = *flag;
    for (int ii = 0; ii < 4; ++ii) {
        int idx = tid + ii * 256;
        int i = idx >> 4, j = (idx & 15) * 4;
        size_t g = (size_t)(kt * 64 + i) * 512 + nt * 64 + j;
        if (fp32) {
            float4 v = *(const float4*)((const float*)src + g);
            T[i][j] = v.x; T[i][j+1] = v.y; T[i][j+2] = v.z; T[i][j+3] = v.w;
        } else {
            ushort4 u = *(const ushort4*)((const unsigned short*)src + g);
            T[i][j] = bf16_to_f(u.x); T[i][j+1] = bf16_to_f(u.y);
            T[i][j+2] = bf16_to_f(u.z); T[i][j+3] = bf16_to_f(u.w);
        }
    }
    __syncthreads();
    for (int ii = 0; ii < 2; ++ii) {
        int idx = tid + ii * 256;
        int j = idx >> 3, ch = idx & 7;
        unsigned short pk[8];
        for (int t = 0; t < 8; ++t) pk[t] = f_to_bf16(T[ch * 8 + t][j]);
        *(bf16x8*)&Wt[(size_t)(mat * 512 + nt * 64 + j) * 512 + kt * 64 + ch * 8] = *(bf16x8*)pk;
    }
}

// ---- 6 small vectors -> bias_all fp32 [6][512]: bq,bk,bv,bo,gamma,beta
__global__ __launch_bounds__(256) void conv_small_kernel(
        const void* b0, const void* b1, const void* b2, const void* b3,
        const void* b4, const void* b5, float* __restrict__ dst, const int* __restrict__ flag) {
    int idx = blockIdx.x * 256 + threadIdx.x;
    int mat = idx >> 9, off = idx & 511;
    const void* src = (mat == 0) ? b0 : (mat == 1) ? b1 : (mat == 2) ? b2 :
                      (mat == 3) ? b3 : (mat == 4) ? b4 : b5;
    float v;
    if (*flag) v = ((const float*)src)[off];
    else       v = bf16_to_f(((const unsigned short*)src)[off]);
    dst[idx] = v;
}

// ---- MFMA GEMM: C = A * Bt^T + bias, 128x128x64 tiles. A chosen per flag.
// If VtOut != null, cols >= 1024 (V block of fused QKV) are written TRANSPOSED
// to VtOut[bh][d][seq] (bf16) instead of to C.
template <typename OutT>
__global__ __launch_bounds__(256) void gemm_mfma_kernel(
        const unsigned short* __restrict__ A_conv, const unsigned short* __restrict__ A_raw,
        const int* __restrict__ flag,
        const unsigned short* __restrict__ Bt,
        const float* __restrict__ bias, OutT* __restrict__ C, int ldc, int scale_cols,
        unsigned short* __restrict__ VtOut) {
    __shared__ unsigned short At[128 * 64];
    __shared__ unsigned short Bs[128 * 64];
    const unsigned short* A = (*flag) ? A_conv : A_raw;
    int tid = threadIdx.x;
    int wave = tid >> 6, lane = tid & 63;
    int l15 = lane & 15, quad = lane >> 4;
    int m0 = blockIdx.y * 128, n0 = blockIdx.x * 128;
    int wm = (wave & 1) * 64, wn = (wave >> 1) * 64;

    int rt = wave * 32 + (lane >> 3);
    int ch = (lane & 7) ^ ((lane >> 3) & 7);
    const unsigned short* ag = A  + (size_t)(m0 + rt) * 512 + ch * 8;
    const unsigned short* bg = Bt + (size_t)(n0 + rt) * 512 + ch * 8;

    f32x4 acc[4][4];
    for (int i = 0; i < 4; ++i) for (int j = 0; j < 4; ++j) acc[i][j] = (f32x4){0.f,0.f,0.f,0.f};

    for (int k0 = 0; k0 < 512; k0 += 64) {
        __syncthreads();
        #pragma unroll
        for (int j = 0; j < 4; ++j) {
            load_lds16(ag + (size_t)(j * 8) * 512 + k0, &At[(wave * 32 + j * 8) * 64]);
            load_lds16(bg + (size_t)(j * 8) * 512 + k0, &Bs[(wave * 32 + j * 8) * 64]);
        }
        __syncthreads();
        #pragma unroll
        for (int ks = 0; ks < 2; ++ks) {
            bf16x8 a[4], b[4];
            #pragma unroll
            for (int f = 0; f < 4; ++f) {
                int pc = ((ks * 4 + quad) ^ (l15 & 7)) * 8;
                a[f] = *(const bf16x8*)&At[(wm + f * 16 + l15) * 64 + pc];
                b[f] = *(const bf16x8*)&Bs[(wn + f * 16 + l15) * 64 + pc];
            }
            #pragma unroll
            for (int fm = 0; fm < 4; ++fm)
                #pragma unroll
                for (int fn = 0; fn < 4; ++fn)
                    acc[fm][fn] = __builtin_amdgcn_mfma_f32_16x16x32_bf16(a[fm], b[fn], acc[fm][fn], 0, 0, 0);
        }
    }
    #pragma unroll
    for (int fm = 0; fm < 4; ++fm) {
        #pragma unroll
        for (int fn = 0; fn < 4; ++fn) {
            int col = n0 + wn + fn * 16 + l15;
            float bia = bias[col];
            float sc = (col < scale_cols) ? QSCALE : 1.f;
            int rowbase = m0 + wm + fm * 16 + quad * 4;
            float v0 = (acc[fm][fn][0] + bia) * sc;
            float v1 = (acc[fm][fn][1] + bia) * sc;
            float v2 = (acc[fm][fn][2] + bia) * sc;
            float v3 = (acc[fm][fn][3] + bia) * sc;
            if (VtOut && col >= 1024) {
                int hd = col - 1024;
                int bh = (rowbase >> 12) * 8 + (hd >> 6);
                int d  = hd & 63;
                ushort4 pk = { f_to_bf16(v0), f_to_bf16(v1), f_to_bf16(v2), f_to_bf16(v3) };
                *(ushort4*)&VtOut[((size_t)(bh * 64 + d)) * SEQ + (rowbase & 4095)] = pk;
            } else {
                if constexpr (sizeof(OutT) == 2) {
                    C[(size_t)(rowbase + 0) * ldc + col] = (OutT)f_to_bf16(v0);
                    C[(size_t)(rowbase + 1) * ldc + col] = (OutT)f_to_bf16(v1);
                    C[(size_t)(rowbase + 2) * ldc + col] = (OutT)f_to_bf16(v2);
                    C[(size_t)(rowbase + 3) * ldc + col] = (OutT)f_to_bf16(v3);
                } else {
                    C[(size_t)(rowbase + 0) * ldc + col] = v0;
                    C[(size_t)(rowbase + 1) * ldc + col] = v1;
                    C[(size_t)(rowbase + 2) * ldc + col] = v2;
                    C[(size_t)(rowbase + 3) * ldc + col] = v3;
                }
            }
        }
    }
}

// ---- MFMA flash attention: LDS-staged K/V + register P. Block = 64 q, 4 waves in
// 2q x 2k split: wave = (qh = wave>>1)*32 q-rows x (kh = wave&1)*64 kcols of each
// 128-k tile. S^T = K·Q^T (swapped operands) -> exp2 -> bf16x4 A-frag -> K16 PV,
// no Ps LDS. Split-K=2, XCD swizzle. Epilogue: cross-kh O/l reduction via LDS.
__global__ __launch_bounds__(256, 4) void attn_kernel(
        const unsigned short* __restrict__ QKV, const unsigned short* __restrict__ Vt,
        float* __restrict__ Opart, float* __restrict__ Lpart) {
    __shared__ __align__(16) unsigned char smem[32768 + 512];
    unsigned short* Ks = (unsigned short*)smem;              // [128 krow][64 d] swizzled
    unsigned short* Vs = (unsigned short*)(smem + 16384);    // [64 d][128 krow] swizzled
    float* Ored = (float*)smem;                              // epilogue [4 w][16 q][64 d]
    float* Lred = (float*)(smem + 32768);                    // [4 w][2 t][16 q]

    int tid = threadIdx.x;
    int wave = tid >> 6, lane = tid & 63;
    int l15 = lane & 15, quad = lane >> 4;
    int qh = wave >> 1, kh = wave & 1;
    // grid 2048 = 8 xcd * 256 slots; grp = xcd + 8*(slot>>6); qt = slot&63
    int lin = blockIdx.x;
    int xcd = lin & 7, slot = lin >> 3;
    int grp = xcd + 8 * (slot >> 6);
    int qt = slot & 63;
    int h = grp & 7, b = (grp >> 3) & 1, s = grp >> 4;
    int bh = b * HEADS + h;
    int k0base = s * (SEQ / SPLIT);
    size_t qrow0 = (size_t)b * SEQ + qt * 64;

    // Q B-frags (n = q = l15, k = d): rows qh*32 + t*16 + l15. Pre-scaled by QSCALE.
    bf16x8 aq[2][2];
    #pragma unroll
    for (int t = 0; t < 2; ++t) {
        const unsigned short* qp = &QKV[(qrow0 + qh * 32 + t * 16 + l15) * 1536 + h * 64];
        aq[t][0] = *(const bf16x8*)&qp[quad * 8];
        aq[t][1] = *(const bf16x8*)&qp[32 + quad * 8];
    }
    f32x4 o[2][4];     // [t][db]: O[q = qh*32+t*16+quad*4+r][d = db*16+l15], partial over kh
    #pragma unroll
    for (int t = 0; t < 2; ++t)
        #pragma unroll
        for (int db = 0; db < 4; ++db) o[t][db] = (f32x4){0.f, 0.f, 0.f, 0.f};
    float lp[2] = {0.f, 0.f};   // per-lane: q = l15, summed over this lane's kcols

    // staging pointers (identical pattern to R9)
    int krt = wave * 32 + (lane >> 3);
    int kch = (lane & 7) ^ ((lane >> 3) & 7);
    const unsigned short* kg =
        &QKV[((size_t)b * SEQ + k0base + krt) * 1536 + 512 + h * 64 + kch * 8];

    for (int kt = 0; kt < SEQ / SPLIT / 128; ++kt) {
        __syncthreads();
        #pragma unroll
        for (int j = 0; j < 4; ++j) {
            load_lds16(kg + (size_t)(kt * 128 + j * 8) * 1536, &Ks[(wave * 32 + j * 8) * 64]);
            int d = wave * 16 + j * 4 + quad;
            int vch = l15 ^ (d & 7);
            load_lds16(&Vt[((size_t)bh * 64 + d) * SEQ + k0base + kt * 128 + vch * 8],
                       &Vs[(wave * 16 + j * 4) * 128]);
        }
        __syncthreads();

        #pragma unroll
        for (int nb = 0; nb < 4; ++nb) {
            int kc = kh * 64 + nb * 16;              // wave's kcol tile base in 128-tile
            // K A-frag (m = kcol = l15 within tile, k = d): rows kc + l15
            int krow = kc + l15;
            int key = krow & 7;
            bf16x8 kA0 = *(const bf16x8*)&Ks[krow * 64 + (quad ^ key) * 8];
            bf16x8 kA1 = *(const bf16x8*)&Ks[krow * 64 + ((4 + quad) ^ key) * 8];
            // V B-frags (k = kcol = quad*4+j, n = d = db*16+l15): 8B reads
            bf16x4 bv[4];
            #pragma unroll
            for (int db = 0; db < 4; ++db) {
                int d = db * 16 + l15;
                int c16 = (kc >> 3) + (quad >> 1);   // 16B chunk index
                int sub = (quad & 1) * 4;
                bv[db] = *(const bf16x4*)&Vs[d * 128 + ((c16 ^ (d & 7)) * 8) + sub];
            }
            #pragma unroll
            for (int t = 0; t < 2; ++t) {
                f32x4 sv = {0.f, 0.f, 0.f, 0.f};
                sv = __builtin_amdgcn_mfma_f32_16x16x32_bf16(kA0, aq[t][0], sv, 0, 0, 0);
                sv = __builtin_amdgcn_mfma_f32_16x16x32_bf16(kA1, aq[t][1], sv, 0, 0, 0);
                float p0 = __builtin_amdgcn_exp2f(sv[0]);
                float p1 = __builtin_amdgcn_exp2f(sv[1]);
                float p2 = __builtin_amdgcn_exp2f(sv[2]);
                float p3 = __builtin_amdgcn_exp2f(sv[3]);
                lp[t] += (p0 + p1) + (p2 + p3);
                union { unsigned int u[2]; bf16x4 v; } ap;
                ap.u[0] = pack_bf16_trunc(p0, p1);
                ap.u[1] = pack_bf16_trunc(p2, p3);
                #pragma unroll
                for (int db = 0; db < 4; ++db)
                    o[t][db] = MFMA_K16(ap.v, bv[db], o[t][db]);
            }
        }
    }

    // ---- epilogue: l over quads (shfl); O/l over kh pairs via LDS (aliases Ks/Vs)
    #pragma unroll
    for (int t = 0; t < 2; ++t) {
        float v = lp[t];
        v += __shfl_xor(v, 16, 64);
        v += __shfl_xor(v, 32, 64);
        if (quad == 0) Lred[(wave * 2 + t) * 16 + l15] = v;
    }
    __syncthreads();
    float* myO = Ored + wave * (16 * 64);
    #pragma unroll
    for (int t = 0; t < 2; ++t) {
        #pragma unroll
        for (int db = 0; db < 4; ++db)
            #pragma unroll
            for (int r = 0; r < 4; ++r)
                myO[(quad * 4 + r) * 64 + db * 16 + l15] = o[t][db][r];
        __syncthreads();
        {
            int q_l = tid >> 3;              // 0..31
            int dg = tid & 7;
            int qh2 = q_l >> 4, qq = q_l & 15;
            const float* r0 = Ored + (qh2 * 2 + 0) * (16 * 64) + qq * 64 + dg * 8;
            const float* r1 = Ored + (qh2 * 2 + 1) * (16 * 64) + qq * 64 + dg * 8;
            float4 a0 = *(const float4*)&r0[0];
            float4 a1 = *(const float4*)&r0[4];
            float4 c0 = *(const float4*)&r1[0];
            float4 c1 = *(const float4*)&r1[4];
            float4 o0 = { a0.x + c0.x, a0.y + c0.y, a0.z + c0.z, a0.w + c0.w };
            float4 o1 = { a1.x + c1.x, a1.y + c1.y, a1.z + c1.z, a1.w + c1.w };
            size_t row = qrow0 + qh2 * 32 + t * 16 + qq;
            float* dst = &Opart[((size_t)s * ROWS + row) * EMB + h * 64 + dg * 8];
            *(float4*)&dst[0] = o0;
            *(float4*)&dst[4] = o1;
            if (dg == 0) {
                float lt = Lred[((qh2 * 2 + 0) * 2 + t) * 16 + qq] +
                           Lred[((qh2 * 2 + 1) * 2 + t) * 16 + qq];
                Lpart[((size_t)s * ROWS + row) * 8 + h] = lt;
            }
        }
        __syncthreads();
    }
}

// ---- merge split-K partials: Ab = (sum_s O_s) / (sum_s l_s), bf16
__global__ __launch_bounds__(256) void merge_kernel(
        const float* __restrict__ Opart, const float* __restrict__ Lpart,
        unsigned short* __restrict__ Ab) {
    int idx4 = (blockIdx.x * 256 + threadIdx.x) * 4;
    int row = idx4 >> 9;
    int h = (idx4 & 511) >> 6;
    float l = 0.f;
    float acc[4] = {0.f, 0.f, 0.f, 0.f};
    #pragma unroll
    for (int s = 0; s < SPLIT; ++s) {
        l += Lpart[((size_t)s * ROWS + row) * 8 + h];
        float4 u = *(const float4*)&Opart[(size_t)s * ROWS * EMB + idx4];
        acc[0] += u.x; acc[1] += u.y; acc[2] += u.z; acc[3] += u.w;
    }
    float inv = 1.f / l;
    ushort4 out = { f_to_bf16(acc[0] * inv), f_to_bf16(acc[1] * inv),
                    f_to_bf16(acc[2] * inv), f_to_bf16(acc[3] * inv) };
    *(ushort4*)&Ab[idx4] = out;
}

// ---- y = x + P; LayerNorm -> out. 4 rows per block (1 wave each).
__global__ __launch_bounds__(256) void ln_kernel(
        const float* __restrict__ xf, const unsigned short* __restrict__ xraw,
        const unsigned short* __restrict__ P,
        const float* __restrict__ gamma, const float* __restrict__ beta,
        void* __restrict__ out, const int* __restrict__ flag) {
    int row = blockIdx.x * 4 + (threadIdx.x >> 6);
    int t = threadIdx.x & 63;
    int fp32 = *flag;
    float v[8];
    float s = 0.f, ss = 0.f;
    const unsigned short* pp = &P[(size_t)row * EMB + t * 8];
    ushort4 p0 = *(const ushort4*)&pp[0];
    ushort4 p1 = *(const ushort4*)&pp[4];
    float pv[8] = { bf16_to_f(p0.x), bf16_to_f(p0.y), bf16_to_f(p0.z), bf16_to_f(p0.w),
                    bf16_to_f(p1.x), bf16_to_f(p1.y), bf16_to_f(p1.z), bf16_to_f(p1.w) };
    if (fp32) {
        const float* xp = &xf[(size_t)row * EMB + t * 8];
        for (int i = 0; i < 8; i += 4) {
            float4 x4 = *(const float4*)&xp[i];
            v[i] = x4.x + pv[i]; v[i+1] = x4.y + pv[i+1];
            v[i+2] = x4.z + pv[i+2]; v[i+3] = x4.w + pv[i+3];
        }
    } else {
        const unsigned short* xp = &xraw[(size_t)row * EMB + t * 8];
        ushort4 x0 = *(const ushort4*)&xp[0];
        ushort4 x1 = *(const ushort4*)&xp[4];
        v[0] = bf16_to_f(x0.x) + pv[0]; v[1] = bf16_to_f(x0.y) + pv[1];
        v[2] = bf16_to_f(x0.z) + pv[2]; v[3] = bf16_to_f(x0.w) + pv[3];
        v[4] = bf16_to_f(x1.x) + pv[4]; v[5] = bf16_to_f(x1.y) + pv[5];
        v[6] = bf16_to_f(x1.z) + pv[6]; v[7] = bf16_to_f(x1.w) + pv[7];
    }
    for (int i = 0; i < 8; ++i) { s += v[i]; ss += v[i] * v[i]; }
    for (int off = 32; off > 0; off >>= 1) {
        s  += __shfl_xor(s, off, 64);
        ss += __shfl_xor(ss, off, 64);
    }
    float mu = s * (1.f / 512.f);
    float var = ss * (1.f / 512.f) - mu * mu;
    float rs = rsqrtf(var + 1e-5f);
    for (int i = 0; i < 8; ++i) {
        int col = t * 8 + i;
        float y = (v[i] - mu) * rs * gamma[col] + beta[col];
        if (fp32) ((float*)out)[(size_t)row * EMB + col] = y;
        else      ((__hip_bfloat16*)out)[(size_t)row * EMB + col] = __float2bfloat16(y);
    }
}

extern "C" void kernel_launch(void* const* d_in, const int* in_sizes, int n_in,
                              void* d_out, int out_size, void* d_ws, size_t ws_size,
                              hipStream_t stream) {
    char* ws = (char*)d_ws;
    int* flag = (int*)ws;
    char* p = ws + 256;
    float* x_f  = (float*)p;           p += (size_t)ROWS * EMB * 4;          // 16MB
    float* bias_all = (float*)p;       p += 6 * 512 * 4;
    unsigned short* Wt   = (unsigned short*)p; p += (size_t)2048 * 512 * 2;  // 2MB
    unsigned short* QKVb = (unsigned short*)p; p += (size_t)ROWS * 1536 * 2; // 24MB
    unsigned short* Vt   = (unsigned short*)p; p += (size_t)16 * HD * SEQ * 2; // 8MB
    // shared region A: xb (conv_x -> QKV gemm) then Ab (merge -> O-proj)
    unsigned short* xb = (unsigned short*)p;
    unsigned short* Ab = (unsigned short*)p;   p += (size_t)ROWS * EMB * 2;  // 8MB
    // shared region B: Opart fp32 (attn -> merge) then Pb (O-proj -> ln)
    float* Opart = (float*)p;
    unsigned short* Pb = (unsigned short*)p;   p += (size_t)SPLIT * ROWS * EMB * 4; // 32MB
    float* Lpart = (float*)p;          p += (size_t)SPLIT * ROWS * 8 * 4;    // 0.5MB

    detect_kernel<<<1, 64, 0, stream>>>(d_in[0], flag);

    conv_x_kernel<<<ROWS * EMB / 1024, 256, 0, stream>>>(d_in[0], x_f, xb, flag);
    conv_wt_kernel<<<dim3(8, 8, 4), 256, 0, stream>>>(d_in[1], d_in[3], d_in[5], d_in[7], Wt, flag);
    conv_small_kernel<<<12, 256, 0, stream>>>(d_in[2], d_in[4], d_in[6], d_in[8], d_in[9], d_in[10],
                                              bias_all, flag);

    // fused QKV: N=1536; Q cols pre-scaled by QSCALE; V cols written transposed to Vt
    gemm_mfma_kernel<unsigned short><<<dim3(12, 64), 256, 0, stream>>>(
        xb, (const unsigned short*)d_in[0], flag, Wt, bias_all, QKVb, 1536, 512, Vt);

    attn_kernel<<<dim3(64 * HEADS * 2 * SPLIT), 256, 0, stream>>>(QKVb, Vt, Opart, Lpart);

    merge_kernel<<<ROWS * EMB / 1024, 256, 0, stream>>>(Opart, Lpart, Ab);

    // O-proj -> bf16
    gemm_mfma_kernel<unsigned short><<<dim3(4, 64), 256, 0, stream>>>(
        Ab, Ab, flag, Wt + (size_t)1536 * 512, bias_all + 1536, Pb, 512, 0,
        (unsigned short*)nullptr);

    ln_kernel<<<ROWS / 4, 256, 0, stream>>>(x_f, (const unsigned short*)d_in[0], Pb,
                                            bias_all + 4 * 512, bias_all + 5 * 512, d_out, flag);
}